// Round 3
// baseline (186.293 us; speedup 1.0000x reference)
//
#include <hip/hip_runtime.h>

#define NSEQ 4096
#define EDIM 1024

// ws layout (float offsets)
#define OFF_HP  0u        // {h_loc, P_inc} [64 chain][4096 t] float2 = 2 MB
#define OFF_SUM 524288u   // {h_last, P_prod} [64 chain][64 chunk] float2 = 32 KB
#define OFF_H0  532480u   // carry-in h [64 chain][64 chunk] float = 16 KB

__device__ __forceinline__ void fma4(float4& a, float xv, const float4& b) {
    a.x = fmaf(xv, b.x, a.x);
    a.y = fmaf(xv, b.y, a.y);
    a.z = fmaf(xv, b.z, a.z);
    a.w = fmaf(xv, b.w, a.w);
}

// ---------------------------------------------------------------------------
// k1: block = 64 consecutive timesteps x FULL e (1024). Computes complete
// Bx[64 rows][16 s] (no cross-block partials -> PBX intermediate eliminated),
// then softplus/exp/64-step wave scan in-kernel, writing {h_loc,P_inc} float2
// + per-chunk summary. 256 blocks x 256 threads (1 block/CU), so staging uses
// 2-deep register prefetch (pfA/pfB) to keep x loads ~2 chunks ahead of the
// vmcnt drain at each stage. LDS pitch 68 floats (17 quads, stride 1 mod 8
// quad-groups): conflict-free b128 reads/writes.
// ---------------------------------------------------------------------------
__global__ __launch_bounds__(256) void k1_bxscan(const float* __restrict__ x,
                                                 const float* __restrict__ A,
                                                 const float* __restrict__ Bin,
                                                 float* __restrict__ ws) {
    __shared__ __align__(16) float smem[2 * 64 * 68];   // 34.8 KB
    const int tid  = threadIdx.x;
    const int lane = tid & 63;                                  // row (= t)
    const int wu   = __builtin_amdgcn_readfirstlane(tid) >> 6;  // wave id
    const int r0   = blockIdx.x * 64;        // global row base (b*4096 + n0)
    const int b    = r0 >> 12;
    const int n0   = r0 & 4095;

    const float4* xf4 = (const float4*)x;
    const float4* Bf4 = (const float4*)Bin;

    float acc[16];
#pragma unroll
    for (int s = 0; s < 16; s++) acc[s] = 0.f;

    float4 pfA[4], pfB[4];
    // chunk 0: load -> stage
#pragma unroll
    for (int k = 0; k < 4; k++) {
        int i = tid + 256 * k, row = i >> 4, cq = i & 15;
        pfA[k] = xf4[(size_t)(r0 + row) * 256 + cq];
    }
#pragma unroll
    for (int k = 0; k < 4; k++) {
        int i = tid + 256 * k, row = i >> 4, cq = i & 15;
        *(float4*)&smem[row * 68 + cq * 4] = pfA[k];
    }
    __syncthreads();
    // issue chunk 1
#pragma unroll
    for (int k = 0; k < 4; k++) {
        int i = tid + 256 * k, row = i >> 4, cq = i & 15;
        pfA[k] = xf4[(size_t)(r0 + row) * 256 + 16 + cq];
    }

    // inner compute for one 64-e chunk; e is wave-uniform -> B via s_loads
    auto compute = [&](int c, const float* stg) {
#pragma unroll
        for (int jj = 0; jj < 4; ++jj) {
            const float4 xq = *(const float4*)&stg[lane * 68 + wu * 16 + jj * 4];
            const float xs[4] = {xq.x, xq.y, xq.z, xq.w};
#pragma unroll
            for (int m = 0; m < 4; ++m) {
                const int e = c * 64 + wu * 16 + jj * 4 + m;   // wave-uniform
                const float4 b0 = Bf4[e * 4 + 0];
                const float4 b1 = Bf4[e * 4 + 1];
                const float4 b2 = Bf4[e * 4 + 2];
                const float4 b3 = Bf4[e * 4 + 3];
                const float xv = xs[m];
                acc[0]  = fmaf(xv, b0.x, acc[0]);  acc[1]  = fmaf(xv, b0.y, acc[1]);
                acc[2]  = fmaf(xv, b0.z, acc[2]);  acc[3]  = fmaf(xv, b0.w, acc[3]);
                acc[4]  = fmaf(xv, b1.x, acc[4]);  acc[5]  = fmaf(xv, b1.y, acc[5]);
                acc[6]  = fmaf(xv, b1.z, acc[6]);  acc[7]  = fmaf(xv, b1.w, acc[7]);
                acc[8]  = fmaf(xv, b2.x, acc[8]);  acc[9]  = fmaf(xv, b2.y, acc[9]);
                acc[10] = fmaf(xv, b2.z, acc[10]); acc[11] = fmaf(xv, b2.w, acc[11]);
                acc[12] = fmaf(xv, b3.x, acc[12]); acc[13] = fmaf(xv, b3.y, acc[13]);
                acc[14] = fmaf(xv, b3.z, acc[14]); acc[15] = fmaf(xv, b3.w, acc[15]);
            }
        }
    };

    // 16 chunks of 64 e, 2-step unrolled with ping-pong prefetch regs.
    // Invariant at loop top (c even): buf[c&1] holds chunk c; pfA = loads(c+1)
    // in flight; pfB free.
    for (int c = 0; c < 16; c += 2) {
        if (c + 2 < 16) {
#pragma unroll
            for (int k = 0; k < 4; k++) {
                int i = tid + 256 * k, row = i >> 4, cq = i & 15;
                pfB[k] = xf4[(size_t)(r0 + row) * 256 + (c + 2) * 16 + cq];
            }
        }
        compute(c, &smem[0]);                         // c even -> buffer 0
        {   // stage chunk c+1 (pfA) into buffer 1
#pragma unroll
            for (int k = 0; k < 4; k++) {
                int i = tid + 256 * k, row = i >> 4, cq = i & 15;
                *(float4*)&smem[4352 + row * 68 + cq * 4] = pfA[k];
            }
        }
        __syncthreads();
        if (c + 3 < 16) {
#pragma unroll
            for (int k = 0; k < 4; k++) {
                int i = tid + 256 * k, row = i >> 4, cq = i & 15;
                pfA[k] = xf4[(size_t)(r0 + row) * 256 + (c + 3) * 16 + cq];
            }
        }
        compute(c + 1, &smem[4352]);
        if (c + 2 < 16) {   // stage chunk c+2 (pfB) into buffer 0
#pragma unroll
            for (int k = 0; k < 4; k++) {
                int i = tid + 256 * k, row = i >> 4, cq = i & 15;
                *(float4*)&smem[row * 68 + cq * 4] = pfB[k];
            }
        }
        __syncthreads();
    }

    // cross-wave reduction: red[4 waves][64 rows][17] aliases buffer 0
    {
        const int rb = (wu * 64 + lane) * 17;
#pragma unroll
        for (int s = 0; s < 16; s++) smem[rb + s] = acc[s];
    }
    __syncthreads();

    // softplus -> decay -> 64-step wave scan; wave wu handles s = wu*4+j
    const int chunk = n0 >> 6;
    float2* HP = (float2*)(ws + OFF_HP);
    float2* SU = (float2*)(ws + OFF_SUM);
#pragma unroll
    for (int j = 0; j < 4; ++j) {
        const int s = wu * 4 + j;                      // wave-uniform
        const float bx = smem[lane * 17 + s] + smem[(64 + lane) * 17 + s] +
                         smem[(128 + lane) * 17 + s] + smem[(192 + lane) * 17 + s];
        const float Ae = expf(A[s]);
        const float sp = fmaxf(bx, 0.f) + log1pf(expf(-fabsf(bx)));
        const float de = expf(-Ae * sp);
        float Pi = de, hi = bx;
#pragma unroll
        for (int off = 1; off < 64; off <<= 1) {
            float Pp = __shfl_up(Pi, off, 64);
            float hp = __shfl_up(hi, off, 64);
            if (lane >= off) { hi = fmaf(hp, Pi, hi); Pi *= Pp; }
        }
        const int chain = b * 16 + s;
        HP[(size_t)chain * NSEQ + n0 + lane] = make_float2(hi, Pi);
        if (lane == 63) SU[chain * 64 + chunk] = make_float2(hi, Pi);
    }
}

// ---------------------------------------------------------------------------
// k2: per-chain wave-scan of the 64 chunk summaries -> exclusive carry-in h
// for every chunk. 64 blocks x 64 threads; ~16 KB of traffic. Dispatch
// boundary provides the cross-block barrier for free.
// ---------------------------------------------------------------------------
__global__ __launch_bounds__(64) void k2_carry(float* __restrict__ ws) {
    const int chain = blockIdx.x;
    const int lane  = threadIdx.x;     // chunk index
    const float2 sv = ((const float2*)(ws + OFF_SUM))[chain * 64 + lane];
    float hi = sv.x, Pi = sv.y;
#pragma unroll
    for (int off = 1; off < 64; off <<= 1) {
        float Pp = __shfl_up(Pi, off, 64);
        float hp = __shfl_up(hi, off, 64);
        if (lane >= off) { hi = fmaf(hp, Pi, hi); Pi *= Pp; }
    }
    float He = __shfl_up(hi, 1, 64);   // exclusive
    if (lane == 0) He = 0.f;
    ws[OFF_H0 + chain * 64 + lane] = He;
}

// ---------------------------------------------------------------------------
// k3: h = fma(P_inc, H0[chunk], h_loc) into a 16x17 LDS tile, then
// y[b,t,e] = sum_s h[t,s]*C[s,e] (+ x*D slow path). 1024 blocks x 256 thr.
// ---------------------------------------------------------------------------
__global__ __launch_bounds__(256) void k3_out(const float* __restrict__ x,
                                              const float* __restrict__ C,
                                              const float* __restrict__ D,
                                              const float* __restrict__ ws,
                                              float* __restrict__ out) {
    __shared__ float sh[16 * 17];
    const int tid = threadIdx.x;
    const int blk = blockIdx.x;
    const int tc  = blk & 255;
    const int b   = blk >> 8;
    const int t0  = tc * 16;

    {   // reconstruct h[tt][s]: thread (s = tid>>4, tt = tid&15)
        const int s  = tid >> 4;
        const int tt = tid & 15;
        const int chain = b * 16 + s;
        const int t = t0 + tt;
        const float2 hp = ((const float2*)(ws + OFF_HP))[(size_t)chain * NSEQ + t];
        const float h0  = ws[OFF_H0 + chain * 64 + (t >> 6)];
        sh[tt * 17 + s] = fmaf(hp.y, h0, hp.x);
    }

    const float4* C4 = (const float4*)C;  // [16][256] float4
    float4 creg[16];
#pragma unroll
    for (int s = 0; s < 16; s++) creg[s] = C4[s * 256 + tid];
    const float4 dreg = ((const float4*)D)[tid];
    const bool needX = __any((dreg.x != 0.f) | (dreg.y != 0.f) |
                             (dreg.z != 0.f) | (dreg.w != 0.f));
    __syncthreads();

    const float4* x4 = (const float4*)x;
    float4* o4 = (float4*)out;
    const size_t rowbase = ((size_t)b * NSEQ + t0) * 256;

    if (needX) {
#pragma unroll 4
        for (int tt = 0; tt < 16; tt++) {
            float4 xv = x4[rowbase + tt * 256 + tid];
            float4 y;
            y.x = xv.x * dreg.x; y.y = xv.y * dreg.y;
            y.z = xv.z * dreg.z; y.w = xv.w * dreg.w;
#pragma unroll
            for (int s = 0; s < 16; s++) fma4(y, sh[tt * 17 + s], creg[s]);
            o4[rowbase + tt * 256 + tid] = y;
        }
    } else {
#pragma unroll 4
        for (int tt = 0; tt < 16; tt++) {
            float4 y = make_float4(0.f, 0.f, 0.f, 0.f);
#pragma unroll
            for (int s = 0; s < 16; s++) fma4(y, sh[tt * 17 + s], creg[s]);
            o4[rowbase + tt * 256 + tid] = y;
        }
    }
}

extern "C" void kernel_launch(void* const* d_in, const int* in_sizes, int n_in,
                              void* d_out, int out_size, void* d_ws, size_t ws_size,
                              hipStream_t stream) {
    const float* x   = (const float*)d_in[0];
    const float* A   = (const float*)d_in[1];
    const float* Bin = (const float*)d_in[2];
    const float* C   = (const float*)d_in[3];
    const float* D   = (const float*)d_in[4];
    float* out = (float*)d_out;
    float* ws  = (float*)d_ws;

    hipLaunchKernelGGL(k1_bxscan, dim3(256),  dim3(256), 0, stream, x, A, Bin, ws);
    hipLaunchKernelGGL(k2_carry,  dim3(64),   dim3(64),  0, stream, ws);
    hipLaunchKernelGGL(k3_out,    dim3(1024), dim3(256), 0, stream, x, C, D, ws, out);
}

// Round 4
// 162.092 us; speedup vs baseline: 1.1493x; 1.1493x over previous
//
#include <hip/hip_runtime.h>

#define NSEQ 4096
#define EDIM 1024

// ws layout (float offsets)
#define OFF_HP  0u        // {h_loc, P_inc} [64 chain][4096 t] float2 = 2 MB
#define OFF_SUM 524288u   // {h_last, P_prod} [64 chain][64 chunk] float2 = 32 KB

__device__ __forceinline__ void fma4(float4& a, float xv, const float4& b) {
    a.x = fmaf(xv, b.x, a.x);
    a.y = fmaf(xv, b.y, a.y);
    a.z = fmaf(xv, b.z, a.z);
    a.w = fmaf(xv, b.w, a.w);
}

// ---------------------------------------------------------------------------
// k1: block = 64 consecutive timesteps x FULL e (1024); computes complete
// Bx[64][16], then softplus/exp/64-step wave scan in-kernel. 256 blocks x
// 512 threads (8 waves = 2 waves/SIMD; launch_bounds(512,2) -> 256-VGPR
// budget, no spill — round 3 failed on a 52-VGPR allocation + 1 wave/SIMD).
// Wave wu covers e-slice [wu*8, wu*8+8) of each 64-e chunk (wave-uniform e
// -> B via s_loads). LDS pitch 68 floats (17 quads, stride 1 mod 8 in 16B
// banks): conflict-free b128. 2-deep register prefetch (pfA/pfB).
// ---------------------------------------------------------------------------
__global__ __launch_bounds__(512, 2) void k1_bxscan(const float* __restrict__ x,
                                                    const float* __restrict__ A,
                                                    const float* __restrict__ Bin,
                                                    float* __restrict__ ws) {
    __shared__ __align__(16) float smem[2 * 64 * 68];   // 34.8 KB (8704 floats)
    const int tid  = threadIdx.x;
    const int lane = tid & 63;                                  // row (= t)
    const int wu   = __builtin_amdgcn_readfirstlane(tid) >> 6;  // wave id 0..7
    const int r0   = blockIdx.x * 64;        // global row base (b*4096 + n0)
    const int b    = r0 >> 12;
    const int n0   = r0 & 4095;

    const float4* xf4 = (const float4*)x;
    const float4* Bf4 = (const float4*)Bin;

    float acc[16];
#pragma unroll
    for (int s = 0; s < 16; s++) acc[s] = 0.f;

    float4 pfA[2], pfB[2];
    // chunk 0: load -> stage (1024 float4, 2 per thread)
#pragma unroll
    for (int k = 0; k < 2; k++) {
        int i = tid + 512 * k, row = i >> 4, cq = i & 15;
        pfA[k] = xf4[(size_t)(r0 + row) * 256 + cq];
    }
#pragma unroll
    for (int k = 0; k < 2; k++) {
        int i = tid + 512 * k, row = i >> 4, cq = i & 15;
        *(float4*)&smem[row * 68 + cq * 4] = pfA[k];
    }
    __syncthreads();
    // issue chunk 1
#pragma unroll
    for (int k = 0; k < 2; k++) {
        int i = tid + 512 * k, row = i >> 4, cq = i & 15;
        pfA[k] = xf4[(size_t)(r0 + row) * 256 + 16 + cq];
    }

    // compute one 64-e chunk; wave's 8-e slice, e wave-uniform -> B s_loads
    auto compute = [&](int c, const float* stg) {
#pragma unroll
        for (int jj = 0; jj < 2; ++jj) {
            const float4 xq = *(const float4*)&stg[lane * 68 + wu * 8 + jj * 4];
            const float xs[4] = {xq.x, xq.y, xq.z, xq.w};
#pragma unroll
            for (int m = 0; m < 4; ++m) {
                const int e = c * 64 + wu * 8 + jj * 4 + m;    // wave-uniform
                const float4 b0 = Bf4[e * 4 + 0];
                const float4 b1 = Bf4[e * 4 + 1];
                const float4 b2 = Bf4[e * 4 + 2];
                const float4 b3 = Bf4[e * 4 + 3];
                const float xv = xs[m];
                acc[0]  = fmaf(xv, b0.x, acc[0]);  acc[1]  = fmaf(xv, b0.y, acc[1]);
                acc[2]  = fmaf(xv, b0.z, acc[2]);  acc[3]  = fmaf(xv, b0.w, acc[3]);
                acc[4]  = fmaf(xv, b1.x, acc[4]);  acc[5]  = fmaf(xv, b1.y, acc[5]);
                acc[6]  = fmaf(xv, b1.z, acc[6]);  acc[7]  = fmaf(xv, b1.w, acc[7]);
                acc[8]  = fmaf(xv, b2.x, acc[8]);  acc[9]  = fmaf(xv, b2.y, acc[9]);
                acc[10] = fmaf(xv, b2.z, acc[10]); acc[11] = fmaf(xv, b2.w, acc[11]);
                acc[12] = fmaf(xv, b3.x, acc[12]); acc[13] = fmaf(xv, b3.y, acc[13]);
                acc[14] = fmaf(xv, b3.z, acc[14]); acc[15] = fmaf(xv, b3.w, acc[15]);
            }
        }
    };

    // 16 chunks of 64 e, 2-step unrolled ping-pong.
    for (int c = 0; c < 16; c += 2) {
        if (c + 2 < 16) {
#pragma unroll
            for (int k = 0; k < 2; k++) {
                int i = tid + 512 * k, row = i >> 4, cq = i & 15;
                pfB[k] = xf4[(size_t)(r0 + row) * 256 + (c + 2) * 16 + cq];
            }
        }
        compute(c, &smem[0]);
        {   // stage chunk c+1 (pfA) into buffer 1
#pragma unroll
            for (int k = 0; k < 2; k++) {
                int i = tid + 512 * k, row = i >> 4, cq = i & 15;
                *(float4*)&smem[4352 + row * 68 + cq * 4] = pfA[k];
            }
        }
        __syncthreads();
        if (c + 3 < 16) {
#pragma unroll
            for (int k = 0; k < 2; k++) {
                int i = tid + 512 * k, row = i >> 4, cq = i & 15;
                pfA[k] = xf4[(size_t)(r0 + row) * 256 + (c + 3) * 16 + cq];
            }
        }
        compute(c + 1, &smem[4352]);
        if (c + 2 < 16) {   // stage chunk c+2 (pfB) into buffer 0
#pragma unroll
            for (int k = 0; k < 2; k++) {
                int i = tid + 512 * k, row = i >> 4, cq = i & 15;
                *(float4*)&smem[row * 68 + cq * 4] = pfB[k];
            }
        }
        __syncthreads();
    }

    // cross-wave reduction: red[8 waves][64 rows][17] = 8704 floats (exact)
    {
        const int rb = (wu * 64 + lane) * 17;
#pragma unroll
        for (int s = 0; s < 16; s++) smem[rb + s] = acc[s];
    }
    __syncthreads();

    // softplus -> decay -> 64-step wave scan; wave wu handles s = wu*2 + j
    const int chunk = n0 >> 6;
    float2* HP = (float2*)(ws + OFF_HP);
    float2* SU = (float2*)(ws + OFF_SUM);
#pragma unroll
    for (int j = 0; j < 2; ++j) {
        const int s = wu * 2 + j;                      // wave-uniform
        float bx = 0.f;
#pragma unroll
        for (int wp = 0; wp < 8; ++wp)
            bx += smem[(wp * 64 + lane) * 17 + s];
        const float Ae = expf(A[s]);
        const float sp = fmaxf(bx, 0.f) + log1pf(expf(-fabsf(bx)));
        const float de = expf(-Ae * sp);
        float Pi = de, hi = bx;
#pragma unroll
        for (int off = 1; off < 64; off <<= 1) {
            float Pp = __shfl_up(Pi, off, 64);
            float hp = __shfl_up(hi, off, 64);
            if (lane >= off) { hi = fmaf(hp, Pi, hi); Pi *= Pp; }
        }
        const int chain = b * 16 + s;
        HP[(size_t)chain * NSEQ + n0 + lane] = make_float2(hi, Pi);
        if (lane == 63) SU[chain * 64 + chunk] = make_float2(hi, Pi);
    }
}

// ---------------------------------------------------------------------------
// k3: carry-in H = fma-scan of <= 63 chunk summaries (8 KB, L2-hot), then
// h = fma(P_inc, H, h_loc) into a 16x17 LDS tile, then
// y[b,t,e] = sum_s h[t,s]*C[s,e] (+ x*D slow path). 1024 blocks x 256 thr.
// (old k2 dispatch folded in here — one less launch gap)
// ---------------------------------------------------------------------------
__global__ __launch_bounds__(256) void k3_out(const float* __restrict__ x,
                                              const float* __restrict__ C,
                                              const float* __restrict__ D,
                                              const float* __restrict__ ws,
                                              float* __restrict__ out) {
    __shared__ float sh[16 * 17];
    const int tid = threadIdx.x;
    const int blk = blockIdx.x;
    const int tc  = blk & 255;
    const int b   = blk >> 8;
    const int t0  = tc * 16;

    {   // reconstruct h[tt][s]: thread (s = tid>>4, tt = tid&15)
        const int s  = tid >> 4;
        const int tt = tid & 15;
        const int chain = b * 16 + s;
        const int t = t0 + tt;
        const int chunk = t >> 6;          // uniform per block
        const float2* SU = (const float2*)(ws + OFF_SUM);
        float H = 0.f;                     // scan state entering this chunk
        for (int c = 0; c < chunk; ++c) {
            const float2 su = SU[chain * 64 + c];
            H = fmaf(H, su.y, su.x);
        }
        const float2 hp = ((const float2*)(ws + OFF_HP))[(size_t)chain * NSEQ + t];
        sh[tt * 17 + s] = fmaf(hp.y, H, hp.x);
    }

    const float4* C4 = (const float4*)C;  // [16][256] float4
    float4 creg[16];
#pragma unroll
    for (int s = 0; s < 16; s++) creg[s] = C4[s * 256 + tid];
    const float4 dreg = ((const float4*)D)[tid];
    const bool needX = __any((dreg.x != 0.f) | (dreg.y != 0.f) |
                             (dreg.z != 0.f) | (dreg.w != 0.f));
    __syncthreads();

    const float4* x4 = (const float4*)x;
    float4* o4 = (float4*)out;
    const size_t rowbase = ((size_t)b * NSEQ + t0) * 256;

    if (needX) {
#pragma unroll 4
        for (int tt = 0; tt < 16; tt++) {
            float4 xv = x4[rowbase + tt * 256 + tid];
            float4 y;
            y.x = xv.x * dreg.x; y.y = xv.y * dreg.y;
            y.z = xv.z * dreg.z; y.w = xv.w * dreg.w;
#pragma unroll
            for (int s = 0; s < 16; s++) fma4(y, sh[tt * 17 + s], creg[s]);
            o4[rowbase + tt * 256 + tid] = y;
        }
    } else {
#pragma unroll 4
        for (int tt = 0; tt < 16; tt++) {
            float4 y = make_float4(0.f, 0.f, 0.f, 0.f);
#pragma unroll
            for (int s = 0; s < 16; s++) fma4(y, sh[tt * 17 + s], creg[s]);
            o4[rowbase + tt * 256 + tid] = y;
        }
    }
}

extern "C" void kernel_launch(void* const* d_in, const int* in_sizes, int n_in,
                              void* d_out, int out_size, void* d_ws, size_t ws_size,
                              hipStream_t stream) {
    const float* x   = (const float*)d_in[0];
    const float* A   = (const float*)d_in[1];
    const float* Bin = (const float*)d_in[2];
    const float* C   = (const float*)d_in[3];
    const float* D   = (const float*)d_in[4];
    float* out = (float*)d_out;
    float* ws  = (float*)d_ws;

    hipLaunchKernelGGL(k1_bxscan, dim3(256),  dim3(512), 0, stream, x, A, Bin, ws);
    hipLaunchKernelGGL(k3_out,    dim3(1024), dim3(256), 0, stream, x, C, D, ws, out);
}

// Round 5
// 146.989 us; speedup vs baseline: 1.2674x; 1.1027x over previous
//
#include <hip/hip_runtime.h>

#define NSEQ 4096
#define EDIM 1024

// ws layout (float offsets)
#define OFF_PBX 0u         // partial Bx [4 q][64 chain][4096 t]      = 4 MB
#define OFF_HP  1048576u   // {h_loc, P_inc} [64 chain][4096] float2  = 2 MB
#define OFF_SUM 2097152u   // {h_last, P_prod} [64 chain][16] float2  = 8 KB

__device__ __forceinline__ void fma4(float4& a, float xv, const float4& b) {
    a.x = fmaf(xv, b.x, a.x);
    a.y = fmaf(xv, b.y, a.y);
    a.z = fmaf(xv, b.z, a.z);
    a.w = fmaf(xv, b.w, a.w);
}

// ---------------------------------------------------------------------------
// k1: partial Bx = x @ B_in over one e-quarter (256 e).
// 1024 blocks (256 row-groups x 4 quarters) x 256 threads -> 4 blocks/CU,
// 16 waves/CU (50% occ): independent blocks hide each other's barrier
// drains (round 4's grid-256 full-e variant capped at 1 block/CU and was
// latency-bound at 48 us). lane = row; wave's 16-e slice is wave-uniform
// (B via s_loads). x staged in double-buffered 64x64 LDS chunks, pitch 68
// (16B-aligned, <=2-way bank aliasing on b128 = free).
// ---------------------------------------------------------------------------
__global__ __launch_bounds__(256, 4) void k1_bx(const float* __restrict__ x,
                                                const float* __restrict__ Bin,
                                                float* __restrict__ ws) {
    __shared__ __align__(16) float smem[2 * 64 * 68];   // 34.8 KB
    const int tid  = threadIdx.x;
    const int lane = tid & 63;                                  // row
    const int wu   = __builtin_amdgcn_readfirstlane(tid) >> 6;  // wave id
    const int q    = blockIdx.x & 3;                            // e-quarter
    const int r0   = (blockIdx.x >> 2) * 64;                    // row base
    const int b    = r0 >> 12;
    const int n0   = r0 & 4095;
    const int eq   = q * 256;

    const float4* xf4 = (const float4*)x;
    const float4* Bf4 = (const float4*)Bin;

    float acc[16];
#pragma unroll
    for (int s = 0; s < 16; s++) acc[s] = 0.f;

    float4 pf[4];
#pragma unroll
    for (int k = 0; k < 4; k++) {
        int i = tid + 256 * k, row = i >> 4, cq = i & 15;
        pf[k] = xf4[(size_t)(r0 + row) * 256 + q * 64 + cq];
    }
#pragma unroll
    for (int k = 0; k < 4; k++) {
        int i = tid + 256 * k, row = i >> 4, cq = i & 15;
        *(float4*)&smem[row * 68 + cq * 4] = pf[k];
    }
    __syncthreads();

    for (int c = 0; c < 4; ++c) {
        if (c < 3) {   // prefetch chunk c+1 into regs
#pragma unroll
            for (int k = 0; k < 4; k++) {
                int i = tid + 256 * k, row = i >> 4, cq = i & 15;
                pf[k] = xf4[(size_t)(r0 + row) * 256 + q * 64 + (c + 1) * 16 + cq];
            }
        }
        const float* stg = &smem[(c & 1) * 4352];
#pragma unroll
        for (int jj = 0; jj < 4; ++jj) {
            const float4 xq = *(const float4*)&stg[lane * 68 + wu * 16 + jj * 4];
            const float xs[4] = {xq.x, xq.y, xq.z, xq.w};
#pragma unroll
            for (int m = 0; m < 4; ++m) {
                const int e = eq + c * 64 + wu * 16 + jj * 4 + m;  // wave-uniform
                const float4 b0 = Bf4[e * 4 + 0];
                const float4 b1 = Bf4[e * 4 + 1];
                const float4 b2 = Bf4[e * 4 + 2];
                const float4 b3 = Bf4[e * 4 + 3];
                const float xv = xs[m];
                acc[0]  = fmaf(xv, b0.x, acc[0]);  acc[1]  = fmaf(xv, b0.y, acc[1]);
                acc[2]  = fmaf(xv, b0.z, acc[2]);  acc[3]  = fmaf(xv, b0.w, acc[3]);
                acc[4]  = fmaf(xv, b1.x, acc[4]);  acc[5]  = fmaf(xv, b1.y, acc[5]);
                acc[6]  = fmaf(xv, b1.z, acc[6]);  acc[7]  = fmaf(xv, b1.w, acc[7]);
                acc[8]  = fmaf(xv, b2.x, acc[8]);  acc[9]  = fmaf(xv, b2.y, acc[9]);
                acc[10] = fmaf(xv, b2.z, acc[10]); acc[11] = fmaf(xv, b2.w, acc[11]);
                acc[12] = fmaf(xv, b3.x, acc[12]); acc[13] = fmaf(xv, b3.y, acc[13]);
                acc[14] = fmaf(xv, b3.z, acc[14]); acc[15] = fmaf(xv, b3.w, acc[15]);
            }
        }
        if (c < 3) {   // stage chunk c+1 into the other buffer
            float* dst = &smem[((c + 1) & 1) * 4352];
#pragma unroll
            for (int k = 0; k < 4; k++) {
                int i = tid + 256 * k, row = i >> 4, cq = i & 15;
                *(float4*)&dst[row * 68 + cq * 4] = pf[k];
            }
        }
        __syncthreads();
    }

    // cross-wave reduction: red[4 waves][64 rows][17] aliases the buffers
    {
        const int rb = (wu * 64 + lane) * 17;
#pragma unroll
        for (int s = 0; s < 16; s++) smem[rb + s] = acc[s];
    }
    __syncthreads();

#pragma unroll
    for (int p = 0; p < 4; p++) {
        const int o   = tid + 256 * p;
        const int s   = o >> 6;      // wave-uniform
        const int row = o & 63;
        const float v = smem[(0 * 64 + row) * 17 + s] + smem[(1 * 64 + row) * 17 + s] +
                        smem[(2 * 64 + row) * 17 + s] + smem[(3 * 64 + row) * 17 + s];
        ws[OFF_PBX + (size_t)q * 262144u + (size_t)(b * 16 + s) * NSEQ + n0 + row] = v;
    }
}

// ---------------------------------------------------------------------------
// k2: sum 4 partial-Bx quarters, softplus -> decay, 256-wide chunk-local
// scan. 1024 blocks x 256 threads; block = (chain, 256-step chunk). Wave
// scan + 4-wave LDS combine. Writes interleaved {h_loc,P_inc} float2 + one
// chunk summary; cross-chunk prefix folded into k3 (dispatch boundary =
// free grid barrier).
// ---------------------------------------------------------------------------
__global__ __launch_bounds__(256) void k2_scan(const float* __restrict__ A,
                                               float* __restrict__ ws) {
    __shared__ float sP[4], sH[4];
    const int tid   = threadIdx.x;
    const int lane  = tid & 63;
    const int w     = tid >> 6;
    const int chain = blockIdx.x >> 4;
    const int chunk = blockIdx.x & 15;
    const int ss    = chain & 15;
    const int t     = chunk * 256 + tid;

    float bxv = 0.f;
#pragma unroll
    for (int q = 0; q < 4; q++)
        bxv += ws[OFF_PBX + (size_t)q * 262144u + (size_t)chain * NSEQ + t];

    const float Ae = expf(A[ss]);
    const float sp = fmaxf(bxv, 0.f) + log1pf(expf(-fabsf(bxv)));
    const float de = expf(-Ae * sp);

    // wave-inclusive scan of (P,h): h' = h_left*P_right + h_right
    float Pi = de, hi = bxv;
#pragma unroll
    for (int off = 1; off < 64; off <<= 1) {
        float Pp = __shfl_up(Pi, off, 64);
        float hp = __shfl_up(hi, off, 64);
        if (lane >= off) { hi = fmaf(hp, Pi, hi); Pi *= Pp; }
    }
    if (lane == 63) { sP[w] = Pi; sH[w] = hi; }
    __syncthreads();
    float Hw = 0.f, Pw = 1.f;
    for (int qq = 0; qq < w; qq++) { Hw = fmaf(Hw, sP[qq], sH[qq]); Pw *= sP[qq]; }

    const float hloc = fmaf(Hw, Pi, hi);   // inclusive within chunk
    const float pinc = Pw * Pi;            // product of de over [chunk start, t]
    ((float2*)(ws + OFF_HP))[(size_t)chain * NSEQ + t] = make_float2(hloc, pinc);
    if (tid == 255)   // whole-chunk summary (h_last, P_prod)
        ((float2*)(ws + OFF_SUM))[chain * 16 + chunk] = make_float2(hloc, pinc);
}

// ---------------------------------------------------------------------------
// k3: carry-in H = fma-scan of <=15 chunk summaries (8 KB, L2-hot), then
// h = fma(P_inc, H, h_loc) into a 16x17 LDS tile, then
// y[b,t,e] = sum_s h[t,s]*C[s,e] (+ x*D slow path). 1024 blocks x 256 thr.
// ---------------------------------------------------------------------------
__global__ __launch_bounds__(256) void k3_out(const float* __restrict__ x,
                                              const float* __restrict__ C,
                                              const float* __restrict__ D,
                                              const float* __restrict__ ws,
                                              float* __restrict__ out) {
    __shared__ float sh[16 * 17];
    const int tid = threadIdx.x;
    const int blk = blockIdx.x;
    const int tc  = blk & 255;
    const int b   = blk >> 8;
    const int t0  = tc * 16;

    {   // reconstruct h[tt][s]: thread (s = tid>>4, tt = tid&15)
        const int s  = tid >> 4;
        const int tt = tid & 15;
        const int chain = b * 16 + s;
        const int t = t0 + tt;
        const int chunk = t >> 8;          // uniform per block
        const float2* SU = (const float2*)(ws + OFF_SUM);
        float H = 0.f;                     // scan state entering this chunk
        for (int c = 0; c < chunk; ++c) {
            const float2 su = SU[chain * 16 + c];
            H = fmaf(H, su.y, su.x);
        }
        const float2 hp = ((const float2*)(ws + OFF_HP))[(size_t)chain * NSEQ + t];
        sh[tt * 17 + s] = fmaf(hp.y, H, hp.x);
    }

    const float4* C4 = (const float4*)C;  // [16][256] float4
    float4 creg[16];
#pragma unroll
    for (int s = 0; s < 16; s++) creg[s] = C4[s * 256 + tid];
    const float4 dreg = ((const float4*)D)[tid];
    const bool needX = __any((dreg.x != 0.f) | (dreg.y != 0.f) |
                             (dreg.z != 0.f) | (dreg.w != 0.f));
    __syncthreads();

    const float4* x4 = (const float4*)x;
    float4* o4 = (float4*)out;
    const size_t rowbase = ((size_t)b * NSEQ + t0) * 256;

    if (needX) {
#pragma unroll 4
        for (int tt = 0; tt < 16; tt++) {
            float4 xv = x4[rowbase + tt * 256 + tid];
            float4 y;
            y.x = xv.x * dreg.x; y.y = xv.y * dreg.y;
            y.z = xv.z * dreg.z; y.w = xv.w * dreg.w;
#pragma unroll
            for (int s = 0; s < 16; s++) fma4(y, sh[tt * 17 + s], creg[s]);
            o4[rowbase + tt * 256 + tid] = y;
        }
    } else {
#pragma unroll 4
        for (int tt = 0; tt < 16; tt++) {
            float4 y = make_float4(0.f, 0.f, 0.f, 0.f);
#pragma unroll
            for (int s = 0; s < 16; s++) fma4(y, sh[tt * 17 + s], creg[s]);
            o4[rowbase + tt * 256 + tid] = y;
        }
    }
}

extern "C" void kernel_launch(void* const* d_in, const int* in_sizes, int n_in,
                              void* d_out, int out_size, void* d_ws, size_t ws_size,
                              hipStream_t stream) {
    const float* x   = (const float*)d_in[0];
    const float* A   = (const float*)d_in[1];
    const float* Bin = (const float*)d_in[2];
    const float* C   = (const float*)d_in[3];
    const float* D   = (const float*)d_in[4];
    float* out = (float*)d_out;
    float* ws  = (float*)d_ws;

    hipLaunchKernelGGL(k1_bx,   dim3(1024), dim3(256), 0, stream, x, Bin, ws);
    hipLaunchKernelGGL(k2_scan, dim3(1024), dim3(256), 0, stream, A, ws);
    hipLaunchKernelGGL(k3_out,  dim3(1024), dim3(256), 0, stream, x, C, D, ws, out);
}

// Round 6
// 133.986 us; speedup vs baseline: 1.3904x; 1.0970x over previous
//
#include <hip/hip_runtime.h>

#define NSEQ 4096
#define EDIM 1024

// ws layout (float offsets)
#define OFF_PBX 0u         // partial Bx [4 q][64 chain][4096 t]      = 4 MB
#define OFF_HP  1048576u   // {h_loc, P_inc} [64 chain][4096] float2  = 2 MB
#define OFF_SUM 2097152u   // {h_last, P_prod} [64 chain][16] float2  = 8 KB

__device__ __forceinline__ void fma4(float4& a, float xv, const float4& b) {
    a.x = fmaf(xv, b.x, a.x);
    a.y = fmaf(xv, b.y, a.y);
    a.z = fmaf(xv, b.z, a.z);
    a.w = fmaf(xv, b.w, a.w);
}

// ---------------------------------------------------------------------------
// k1: partial Bx = x @ B_in over one e-quarter (256 e), NO LDS staging.
// Waves PARTITION e (no cross-wave x reuse), so staging x through LDS was a
// pure re-layout cost: 8 barriers + ds traffic for nothing. Instead each
// thread (row = lane, wave = 16-e slice per 64-e chunk) loads its 16 float4
// of x directly into registers (4 x 64B contiguous segments per row; every
// 128B line fully consumed within the block) and runs 1024 FMAs. No
// __syncthreads until the cross-wave reduction. 1024 blocks x 256 threads =
// 4 blocks/CU, 16 waves/CU; VGPR ~90 < 128 budget (no spill).
// B is wave-uniform -> s_loads.
// ---------------------------------------------------------------------------
__global__ __launch_bounds__(256, 4) void k1_bx(const float* __restrict__ x,
                                                const float* __restrict__ Bin,
                                                float* __restrict__ ws) {
    __shared__ float red[4 * 64 * 17];   // 17.4 KB (reduction only)
    const int tid  = threadIdx.x;
    const int lane = tid & 63;                                  // row
    const int wu   = __builtin_amdgcn_readfirstlane(tid) >> 6;  // wave id
    const int q    = blockIdx.x & 3;                            // e-quarter
    const int r0   = (blockIdx.x >> 2) * 64;                    // row base
    const int b    = r0 >> 12;
    const int n0   = r0 & 4095;
    const int eq   = q * 256;

    const float4* xf4 = (const float4*)x;
    const float4* Bf4 = (const float4*)Bin;

    // this thread's x: row r0+lane, e-locals {c*64 + wu*16 + 0..15}, c=0..3
    // float4 index within row-quarter: c*16 + wu*4 + jj
    float4 xr[16];
    const size_t rowb = (size_t)(r0 + lane) * 256 + q * 64 + wu * 4;
#pragma unroll
    for (int c = 0; c < 4; c++)
#pragma unroll
        for (int jj = 0; jj < 4; jj++)
            xr[c * 4 + jj] = xf4[rowb + c * 16 + jj];

    float acc[16];
#pragma unroll
    for (int s = 0; s < 16; s++) acc[s] = 0.f;

#pragma unroll
    for (int c = 0; c < 4; ++c) {
#pragma unroll
        for (int jj = 0; jj < 4; ++jj) {
            const float4 xq = xr[c * 4 + jj];
            const float xs[4] = {xq.x, xq.y, xq.z, xq.w};
#pragma unroll
            for (int m = 0; m < 4; ++m) {
                const int e = eq + c * 64 + wu * 16 + jj * 4 + m;  // wave-uniform
                const float4 b0 = Bf4[e * 4 + 0];
                const float4 b1 = Bf4[e * 4 + 1];
                const float4 b2 = Bf4[e * 4 + 2];
                const float4 b3 = Bf4[e * 4 + 3];
                const float xv = xs[m];
                acc[0]  = fmaf(xv, b0.x, acc[0]);  acc[1]  = fmaf(xv, b0.y, acc[1]);
                acc[2]  = fmaf(xv, b0.z, acc[2]);  acc[3]  = fmaf(xv, b0.w, acc[3]);
                acc[4]  = fmaf(xv, b1.x, acc[4]);  acc[5]  = fmaf(xv, b1.y, acc[5]);
                acc[6]  = fmaf(xv, b1.z, acc[6]);  acc[7]  = fmaf(xv, b1.w, acc[7]);
                acc[8]  = fmaf(xv, b2.x, acc[8]);  acc[9]  = fmaf(xv, b2.y, acc[9]);
                acc[10] = fmaf(xv, b2.z, acc[10]); acc[11] = fmaf(xv, b2.w, acc[11]);
                acc[12] = fmaf(xv, b3.x, acc[12]); acc[13] = fmaf(xv, b3.y, acc[13]);
                acc[14] = fmaf(xv, b3.z, acc[14]); acc[15] = fmaf(xv, b3.w, acc[15]);
            }
        }
    }

    // cross-wave reduction: red[4 waves][64 rows][17]
    {
        const int rb = (wu * 64 + lane) * 17;
#pragma unroll
        for (int s = 0; s < 16; s++) red[rb + s] = acc[s];
    }
    __syncthreads();

#pragma unroll
    for (int p = 0; p < 4; p++) {
        const int o   = tid + 256 * p;
        const int s   = o >> 6;      // wave-uniform
        const int row = o & 63;
        const float v = red[(0 * 64 + row) * 17 + s] + red[(1 * 64 + row) * 17 + s] +
                        red[(2 * 64 + row) * 17 + s] + red[(3 * 64 + row) * 17 + s];
        ws[OFF_PBX + (size_t)q * 262144u + (size_t)(b * 16 + s) * NSEQ + n0 + row] = v;
    }
}

// ---------------------------------------------------------------------------
// k2: sum 4 partial-Bx quarters, softplus -> decay, 256-wide chunk-local
// scan. 1024 blocks x 256 threads; block = (chain, 256-step chunk). Wave
// scan + 4-wave LDS combine. Writes interleaved {h_loc,P_inc} float2 + one
// chunk summary; cross-chunk prefix folded into k3.
// ---------------------------------------------------------------------------
__global__ __launch_bounds__(256) void k2_scan(const float* __restrict__ A,
                                               float* __restrict__ ws) {
    __shared__ float sP[4], sH[4];
    const int tid   = threadIdx.x;
    const int lane  = tid & 63;
    const int w     = tid >> 6;
    const int chain = blockIdx.x >> 4;
    const int chunk = blockIdx.x & 15;
    const int ss    = chain & 15;
    const int t     = chunk * 256 + tid;

    float bxv = 0.f;
#pragma unroll
    for (int q = 0; q < 4; q++)
        bxv += ws[OFF_PBX + (size_t)q * 262144u + (size_t)chain * NSEQ + t];

    const float Ae = expf(A[ss]);
    const float sp = fmaxf(bxv, 0.f) + log1pf(expf(-fabsf(bxv)));
    const float de = expf(-Ae * sp);

    // wave-inclusive scan of (P,h): h' = h_left*P_right + h_right
    float Pi = de, hi = bxv;
#pragma unroll
    for (int off = 1; off < 64; off <<= 1) {
        float Pp = __shfl_up(Pi, off, 64);
        float hp = __shfl_up(hi, off, 64);
        if (lane >= off) { hi = fmaf(hp, Pi, hi); Pi *= Pp; }
    }
    if (lane == 63) { sP[w] = Pi; sH[w] = hi; }
    __syncthreads();
    float Hw = 0.f, Pw = 1.f;
    for (int qq = 0; qq < w; qq++) { Hw = fmaf(Hw, sP[qq], sH[qq]); Pw *= sP[qq]; }

    const float hloc = fmaf(Hw, Pi, hi);   // inclusive within chunk
    const float pinc = Pw * Pi;            // product of de over [chunk start, t]
    ((float2*)(ws + OFF_HP))[(size_t)chain * NSEQ + t] = make_float2(hloc, pinc);
    if (tid == 255)   // whole-chunk summary (h_last, P_prod)
        ((float2*)(ws + OFF_SUM))[chain * 16 + chunk] = make_float2(hloc, pinc);
}

// ---------------------------------------------------------------------------
// k3: carry-in H = fma-scan of <=15 chunk summaries (8 KB, L2-hot), then
// h = fma(P_inc, H, h_loc) into a 16x20 LDS tile (pitch 20: 16B-aligned per
// row -> broadcast ds_read_b128, 4x fewer LDS instrs), then
// y[b,t,e] = sum_s h[t,s]*C[s,e] (+ x*D slow path). 1024 blocks x 256 thr.
// ---------------------------------------------------------------------------
__global__ __launch_bounds__(256) void k3_out(const float* __restrict__ x,
                                              const float* __restrict__ C,
                                              const float* __restrict__ D,
                                              const float* __restrict__ ws,
                                              float* __restrict__ out) {
    __shared__ __align__(16) float sh[16 * 20];
    const int tid = threadIdx.x;
    const int blk = blockIdx.x;
    const int tc  = blk & 255;
    const int b   = blk >> 8;
    const int t0  = tc * 16;

    {   // reconstruct h[tt][s]: thread (s = tid>>4, tt = tid&15)
        const int s  = tid >> 4;
        const int tt = tid & 15;
        const int chain = b * 16 + s;
        const int t = t0 + tt;
        const int chunk = t >> 8;          // uniform per block
        const float2* SU = (const float2*)(ws + OFF_SUM);
        float H = 0.f;                     // scan state entering this chunk
        for (int c = 0; c < chunk; ++c) {
            const float2 su = SU[chain * 16 + c];
            H = fmaf(H, su.y, su.x);
        }
        const float2 hp = ((const float2*)(ws + OFF_HP))[(size_t)chain * NSEQ + t];
        sh[tt * 20 + s] = fmaf(hp.y, H, hp.x);
    }

    const float4* C4 = (const float4*)C;  // [16][256] float4
    float4 creg[16];
#pragma unroll
    for (int s = 0; s < 16; s++) creg[s] = C4[s * 256 + tid];
    const float4 dreg = ((const float4*)D)[tid];
    const bool needX = __any((dreg.x != 0.f) | (dreg.y != 0.f) |
                             (dreg.z != 0.f) | (dreg.w != 0.f));
    __syncthreads();

    const float4* x4 = (const float4*)x;
    float4* o4 = (float4*)out;
    const size_t rowbase = ((size_t)b * NSEQ + t0) * 256;

    if (needX) {
#pragma unroll 4
        for (int tt = 0; tt < 16; tt++) {
            float4 xv = x4[rowbase + tt * 256 + tid];
            float4 y;
            y.x = xv.x * dreg.x; y.y = xv.y * dreg.y;
            y.z = xv.z * dreg.z; y.w = xv.w * dreg.w;
#pragma unroll
            for (int g = 0; g < 4; g++) {
                const float4 h4 = *(const float4*)&sh[tt * 20 + g * 4];
                fma4(y, h4.x, creg[g * 4 + 0]);
                fma4(y, h4.y, creg[g * 4 + 1]);
                fma4(y, h4.z, creg[g * 4 + 2]);
                fma4(y, h4.w, creg[g * 4 + 3]);
            }
            o4[rowbase + tt * 256 + tid] = y;
        }
    } else {
#pragma unroll 4
        for (int tt = 0; tt < 16; tt++) {
            float4 y = make_float4(0.f, 0.f, 0.f, 0.f);
#pragma unroll
            for (int g = 0; g < 4; g++) {
                const float4 h4 = *(const float4*)&sh[tt * 20 + g * 4];
                fma4(y, h4.x, creg[g * 4 + 0]);
                fma4(y, h4.y, creg[g * 4 + 1]);
                fma4(y, h4.z, creg[g * 4 + 2]);
                fma4(y, h4.w, creg[g * 4 + 3]);
            }
            o4[rowbase + tt * 256 + tid] = y;
        }
    }
}

extern "C" void kernel_launch(void* const* d_in, const int* in_sizes, int n_in,
                              void* d_out, int out_size, void* d_ws, size_t ws_size,
                              hipStream_t stream) {
    const float* x   = (const float*)d_in[0];
    const float* A   = (const float*)d_in[1];
    const float* Bin = (const float*)d_in[2];
    const float* C   = (const float*)d_in[3];
    const float* D   = (const float*)d_in[4];
    float* out = (float*)d_out;
    float* ws  = (float*)d_ws;

    hipLaunchKernelGGL(k1_bx,   dim3(1024), dim3(256), 0, stream, x, Bin, ws);
    hipLaunchKernelGGL(k2_scan, dim3(1024), dim3(256), 0, stream, A, ws);
    hipLaunchKernelGGL(k3_out,  dim3(1024), dim3(256), 0, stream, x, C, D, ws, out);
}